// Round 10
// baseline (251.298 us; speedup 1.0000x reference)
//
#include <hip/hip_runtime.h>
#include <cstdint>
#include <cstddef>

typedef unsigned short u16;
typedef __attribute__((ext_vector_type(8))) short bf16x8;
typedef __attribute__((ext_vector_type(8))) unsigned short u16x8;
typedef __attribute__((ext_vector_type(4))) unsigned short u16x4;
typedef __attribute__((ext_vector_type(4))) float f32x4;

// ---------- helpers ----------
__device__ __forceinline__ u16 f2b(float f) {
    union { float f; uint32_t u; } v; v.f = f;
    uint32_t u = v.u;
    uint32_t r = (u + 0x7FFFu + ((u >> 16) & 1u)) >> 16;
    return (u16)r;
}
__device__ __forceinline__ float b2f(u16 b) {
    union { uint32_t u; float f; } v; v.u = ((uint32_t)b) << 16;
    return v.f;
}
__device__ __forceinline__ void gload_lds16(const void* g, void* l) {
    __builtin_amdgcn_global_load_lds(
        (const __attribute__((address_space(1))) void*)g,
        (__attribute__((address_space(3))) void*)l,
        16, 0, 0);
}

// ---------- prep building blocks ----------
// 64x64 f32 tile transpose -> bf16, 256 threads
__device__ __forceinline__ void transpose64_256(const float* __restrict__ in,
                                                u16* __restrict__ outp,
                                                int K, int N, int t, int tid,
                                                float (*tile)[65]) {
    const int ntx = N >> 6;
    const int n0 = (t % ntx) * 64, k0 = (t / ntx) * 64;
    const int r0 = tid >> 4, c4 = tid & 15;
#pragma unroll
    for (int j = 0; j < 4; ++j) {
        int r = r0 + j * 16;
        float4 v = *(const float4*)(in + (size_t)(k0 + r) * N + n0 + c4 * 4);
        tile[r][c4 * 4 + 0] = v.x; tile[r][c4 * 4 + 1] = v.y;
        tile[r][c4 * 4 + 2] = v.z; tile[r][c4 * 4 + 3] = v.w;
    }
    __syncthreads();
    const int rr = tid >> 2;
#pragma unroll
    for (int j = 0; j < 4; ++j) {
        int ch = (tid & 3) + j * 4;
        u16x4 o;
        o[0] = f2b(tile[ch * 4 + 0][rr]); o[1] = f2b(tile[ch * 4 + 1][rr]);
        o[2] = f2b(tile[ch * 4 + 2][rr]); o[3] = f2b(tile[ch * 4 + 3][rr]);
        *(u16x4*)(outp + (size_t)(n0 + rr) * K + k0 + ch * 4) = o;
    }
    __syncthreads();
}

// 64x64 f32 tile transpose -> bf16, 512 threads
__device__ __forceinline__ void transpose64_512(const float* __restrict__ in,
                                                u16* __restrict__ outp,
                                                int K, int N, int t, int tid,
                                                float (*tile)[65]) {
    const int ntx = N >> 6;
    const int n0 = (t % ntx) * 64, k0 = (t / ntx) * 64;
    const int r0 = tid >> 4, c4 = tid & 15;
#pragma unroll
    for (int j = 0; j < 2; ++j) {
        int r = r0 + j * 32;
        float4 v = *(const float4*)(in + (size_t)(k0 + r) * N + n0 + c4 * 4);
        tile[r][c4 * 4 + 0] = v.x; tile[r][c4 * 4 + 1] = v.y;
        tile[r][c4 * 4 + 2] = v.z; tile[r][c4 * 4 + 3] = v.w;
    }
    __syncthreads();
    const int rr = tid >> 3;
#pragma unroll
    for (int j = 0; j < 2; ++j) {
        int ch = (tid & 7) + j * 8;
        u16x4 o;
        o[0] = f2b(tile[ch * 4 + 0][rr]); o[1] = f2b(tile[ch * 4 + 1][rr]);
        o[2] = f2b(tile[ch * 4 + 2][rr]); o[3] = f2b(tile[ch * 4 + 3][rr]);
        *(u16x4*)(outp + (size_t)(n0 + rr) * K + k0 + ch * 4) = o;
    }
    __syncthreads();
}

// ---------- prep1 (256 thr, 898 blocks) ----------
// [0,256)    feat [4096,1024] f32->bf16: 524288 8-elem units,
//            256 blocks x 256 thr x 8 units (EXACT cover, no overrun)
// [256,384)  W1 [1024,2048] -> W1T [2048,1024] bf16 (512 tiles, 4/block)
// [384,386)  b34[j] = b3 . Wh[:,j] + bh[j]   (f32)
// [386,898)  W34b = bf16(W3 @ Wh) via f32 VALU: 512 blocks x 4 rows
__global__ __launch_bounds__(256) void prep1_kernel(
    const float* __restrict__ feat, u16* __restrict__ featB,
    const float* __restrict__ W1, u16* __restrict__ W1T,
    const float* __restrict__ W3, const float* __restrict__ Wh,
    const float* __restrict__ b3, const float* __restrict__ bh,
    float* __restrict__ b34, u16* __restrict__ W34b) {
    __shared__ float tile[64][65];
    const int b = blockIdx.x, tid = threadIdx.x;

    if (b < 256) {  // feat cvt: unit u = b*2048 + it*256 + tid, u < 524288
#pragma unroll
        for (int it = 0; it < 8; ++it) {
            size_t u = (size_t)b * 2048 + (size_t)it * 256 + tid;
            size_t base = u * 8;
            const float4* p = (const float4*)(feat + base);
            float4 a = p[0], c = p[1];
            u16x8 o;
            o[0] = f2b(a.x); o[1] = f2b(a.y); o[2] = f2b(a.z); o[3] = f2b(a.w);
            o[4] = f2b(c.x); o[5] = f2b(c.y); o[6] = f2b(c.z); o[7] = f2b(c.w);
            *(u16x8*)(featB + base) = o;
        }
        return;
    }
    if (b < 384) {  // W1T: 512 tiles, 4 per block
        int g = b - 256;
#pragma unroll
        for (int j = 0; j < 4; ++j)
            transpose64_256(W1, W1T, 1024, 2048, g * 4 + j, tid, tile);
        return;
    }
    if (b < 386) {  // b34
        int j = (b - 384) * 256 + tid;  // [0,512)
        float s = bh[j];
#pragma unroll 4
        for (int k = 0; k < 1024; ++k)
            s += b3[k] * Wh[(size_t)k * 512 + j];
        b34[j] = s;
        return;
    }
    {   // W34b[i][j] = bf16( sum_k W3[i][k] * Wh[k][j] ), f32 accum
        int g = b - 386;             // [0,512)
        int i = g * 4 + (tid >> 6);  // row of W34 [0,2048)
        int j0 = (tid & 63) * 8;     // col group [0,512)
        const float* w3r = W3 + (size_t)i * 1024;
        float s0 = 0, s1 = 0, s2 = 0, s3 = 0, s4 = 0, s5 = 0, s6 = 0, s7 = 0;
#pragma unroll 4
        for (int k = 0; k < 1024; ++k) {
            float a = w3r[k];
            const float* hr = Wh + (size_t)k * 512 + j0;
            float4 h0 = *(const float4*)hr;
            float4 h1 = *(const float4*)(hr + 4);
            s0 += a * h0.x; s1 += a * h0.y; s2 += a * h0.z; s3 += a * h0.w;
            s4 += a * h1.x; s5 += a * h1.y; s6 += a * h1.z; s7 += a * h1.w;
        }
        u16x8 o;
        o[0] = f2b(s0); o[1] = f2b(s1); o[2] = f2b(s2); o[3] = f2b(s3);
        o[4] = f2b(s4); o[5] = f2b(s5); o[6] = f2b(s6); o[7] = f2b(s7);
        *(u16x8*)(W34b + (size_t)i * 512 + j0) = o;
    }
}

// =====================================================================
// 256x128-tile pipelined GEMM core (round-8-verified).
// BK=64, 512 thr = 8 waves (4m x 2n), per-wave 64x64, acc[4][4].
// LDS: 3 buffers x (A 32KB + B 16KB) = 144KB; counted vmcnt(6) gates;
// XOR swizzle ch=(c&7)^(r&7); setprio around MFMA clusters.
// =====================================================================

__device__ __forceinline__ void stage_q(const u16* __restrict__ g, int ldg,
                                        u16* lds, int tid) {
    int r = tid >> 3;
    int ch = (tid & 7) ^ (r & 7);
    gload_lds16(g + (size_t)r * ldg + ch * 8, (char*)lds + tid * 16);
}

__device__ __forceinline__ bf16x8 lds_frag(const u16* s, int row, int kk, int lg) {
    int byte = (row << 7) + (kk << 6) + (lg << 4);
    byte ^= (row & 7) << 4;
    return *(const bf16x8*)((const char*)s + byte);
}

#define MFMA_CLUSTER(AF, BF)                                                   \
    do {                                                                       \
        __builtin_amdgcn_s_setprio(1);                                         \
        _Pragma("unroll") for (int m = 0; m < 4; ++m)                          \
            _Pragma("unroll") for (int n = 0; n < 4; ++n)                      \
                acc[m][n] = __builtin_amdgcn_mfma_f32_16x16x32_bf16(           \
                    AF[m], BF[n], acc[m][n], 0, 0, 0);                         \
        __builtin_amdgcn_s_setprio(0);                                         \
    } while (0)

__device__ __forceinline__ void gemm_loop(
    const u16* __restrict__ Ag, const u16* __restrict__ Bg, int K,
    u16* sA, u16* sB, f32x4 (&acc)[4][4],
    int tid, int wm, int wn, int lr, int lg) {
    const int nt = K >> 6;
    stage_q(Ag, K, sA, tid);
    stage_q(Ag + (size_t)64 * K, K, sA + 4096, tid);
    stage_q(Ag + (size_t)128 * K, K, sA + 8192, tid);
    stage_q(Ag + (size_t)192 * K, K, sA + 12288, tid);
    stage_q(Bg, K, sB, tid);
    stage_q(Bg + (size_t)64 * K, K, sB + 4096, tid);
    stage_q(Ag + 64, K, sA + 16384, tid);
    stage_q(Ag + (size_t)64 * K + 64, K, sA + 16384 + 4096, tid);
    stage_q(Ag + (size_t)128 * K + 64, K, sA + 16384 + 8192, tid);
    stage_q(Ag + (size_t)192 * K + 64, K, sA + 16384 + 12288, tid);
    stage_q(Bg + 64, K, sB + 8192, tid);
    stage_q(Bg + (size_t)64 * K + 64, K, sB + 8192 + 4096, tid);
    asm volatile("s_waitcnt vmcnt(6)" ::: "memory");
    __builtin_amdgcn_sched_barrier(0);
    __builtin_amdgcn_s_barrier();

    for (int t = 0; t < nt; ++t) {
        const int cb = t % 3, nb = (t + 2) % 3;
        const u16* sAc = sA + cb * 16384;
        const u16* sBc = sB + cb * 8192;
        u16* sAn = sA + nb * 16384;
        u16* sBn = sB + nb * 8192;
        const int kb = (t + 2) << 6;
        const bool more2 = (t + 2) < nt;

        // ---- phase 0: kk=0 ----
        bf16x8 a0[4], b0[4];
#pragma unroll
        for (int m = 0; m < 4; ++m)
            a0[m] = lds_frag(sAc + wm * 4096, m * 16 + lr, 0, lg);
#pragma unroll
        for (int n = 0; n < 4; ++n)
            b0[n] = lds_frag(sBc + wn * 4096, n * 16 + lr, 0, lg);
        if (more2) {
            stage_q(Bg + kb, K, sBn, tid);
            stage_q(Bg + (size_t)64 * K + kb, K, sBn + 4096, tid);
            stage_q(Ag + kb, K, sAn, tid);
        }
        asm volatile("s_waitcnt lgkmcnt(0)" ::: "memory");
        __builtin_amdgcn_sched_barrier(0);
        MFMA_CLUSTER(a0, b0);
        __builtin_amdgcn_s_barrier();

        // ---- phase 1: kk=1; gate ----
        bf16x8 a1[4], b1[4];
#pragma unroll
        for (int m = 0; m < 4; ++m)
            a1[m] = lds_frag(sAc + wm * 4096, m * 16 + lr, 1, lg);
#pragma unroll
        for (int n = 0; n < 4; ++n)
            b1[n] = lds_frag(sBc + wn * 4096, n * 16 + lr, 1, lg);
        if (more2) {
            stage_q(Ag + (size_t)64 * K + kb, K, sAn + 4096, tid);
            stage_q(Ag + (size_t)128 * K + kb, K, sAn + 8192, tid);
            stage_q(Ag + (size_t)192 * K + kb, K, sAn + 12288, tid);
            asm volatile("s_waitcnt vmcnt(6)" ::: "memory");
        } else if (t + 1 < nt) {
            asm volatile("s_waitcnt vmcnt(0)" ::: "memory");
        }
        __builtin_amdgcn_sched_barrier(0);
        asm volatile("s_waitcnt lgkmcnt(0)" ::: "memory");
        __builtin_amdgcn_sched_barrier(0);
        MFMA_CLUSTER(a1, b1);
        __builtin_amdgcn_s_barrier();
    }
}

template <int RELU, int HB>
__device__ __forceinline__ void gemm_store(
    const u16* __restrict__ A, const u16* __restrict__ BT,
    const float* __restrict__ bias, u16* __restrict__ C,
    int N, int K, int bx, int by, u16* sA, u16* sB) {
    const int tid = threadIdx.x;
    const int lane = tid & 63;
    const int wv = tid >> 6;
    const int wm = wv >> 1, wn = wv & 1;
    const int lr = lane & 15, lg = lane >> 4;
    const int rowBase = by * 256, colBase = bx * 128;
    f32x4 acc[4][4] = {};
    gemm_loop(A + (size_t)rowBase * K, BT + (size_t)colBase * K, K,
              sA, sB, acc, tid, wm, wn, lr, lg);
#pragma unroll
    for (int n = 0; n < 4; ++n) {
        int col = colBase + wn * 64 + n * 16 + lr;
        float bv = HB ? bias[col] : 0.f;
#pragma unroll
        for (int m = 0; m < 4; ++m) {
            int row0 = rowBase + wm * 64 + m * 16 + lg * 4;
#pragma unroll
            for (int i = 0; i < 4; ++i) {
                float v = acc[m][n][i] + bv;
                if (RELU) v = v > 0.f ? v : 0.f;
                C[(size_t)(row0 + i) * N + col] = f2b(v);
            }
        }
    }
}

// ---------- K2: midA (512 thr, 1800 blocks) ----------
// [0,256)      GEMM1: h1 = relu(featB @ W1T^T + b1)  M=4096 N=2048 K=1024
// [256,264)    out[n] = c[n] = b34 . w[:,n]
// [264,1288)   W2 [2048,2048] -> W2T (1024 64x64 tiles)
// [1288,1800)  w  [512,4096]  -> wTb (512 tiles)
__global__ __launch_bounds__(512, 2) void midA_kernel(
    const u16* __restrict__ featB, const u16* __restrict__ W1T,
    const float* __restrict__ b1, u16* __restrict__ h1,
    const float* __restrict__ b34, const float* __restrict__ w,
    float* __restrict__ out,
    const float* __restrict__ W2, u16* __restrict__ W2T,
    u16* __restrict__ wTb) {
    __shared__ __align__(16) u16 sA[3 * 16384];
    __shared__ __align__(16) u16 sB[3 * 8192];
    const int b = blockIdx.x, tid = threadIdx.x;
    if (b < 256) {
        gemm_store<1, 1>(featB, W1T, b1, h1, 2048, 1024, b & 15, b >> 4, sA, sB);
    } else if (b < 264) {
        int n = (b - 256) * 512 + tid;  // [0,4096)
        float s = 0.f;
#pragma unroll 4
        for (int j = 0; j < 512; ++j)
            s += b34[j] * w[(size_t)j * 4096 + n];
        out[n] = s;
    } else if (b < 1288) {
        transpose64_512(W2, W2T, 2048, 2048, b - 264, tid, (float(*)[65])sA);
    } else {
        transpose64_512(w, wTb, 512, 4096, b - 1288, tid, (float(*)[65])sA);
    }
}

// ---------- K3: fused UT + GEMM2 + row-dot (512 thr, 256 blocks) ----------
__global__ __launch_bounds__(512, 2) void gemm2dot_kernel(
    const u16* __restrict__ h1, const u16* __restrict__ W2T,
    const float* __restrict__ b2,
    const u16* __restrict__ wTb, const u16* __restrict__ W34b,
    float* __restrict__ out) {
    __shared__ __align__(16) u16 sA[3 * 16384];
    __shared__ __align__(16) u16 sB[3 * 8192];
    const int tid = threadIdx.x;
    const int lane = tid & 63;
    const int wv = tid >> 6;
    const int wm = wv >> 1, wn = wv & 1;
    const int lr = lane & 15, lg = lane >> 4;
    const int by = blockIdx.x >> 4, bx = blockIdx.x & 15;
    const int rowBase = by * 256, colBase = bx * 128;

    f32x4 acc[4][4] = {};
    // phase A: UT sub-tile in registers (K=512)
    gemm_loop(wTb + (size_t)rowBase * 512, W34b + (size_t)colBase * 512, 512,
              sA, sB, acc, tid, wm, wn, lr, lg);
    u16x4 ut16[4][4];
#pragma unroll
    for (int m = 0; m < 4; ++m)
#pragma unroll
        for (int n = 0; n < 4; ++n) {
#pragma unroll
            for (int i = 0; i < 4; ++i) ut16[m][n][i] = f2b(acc[m][n][i]);
            acc[m][n] = (f32x4){0.f, 0.f, 0.f, 0.f};
        }
    // phase B: GEMM2 (K=2048)
    gemm_loop(h1 + (size_t)rowBase * 2048, W2T + (size_t)colBase * 2048, 2048,
              sA, sB, acc, tid, wm, wn, lr, lg);
    // epilogue: relu + dot with ut16, lane-reduce, atomicAdd
    float psum[4][4] = {};
#pragma unroll
    for (int n = 0; n < 4; ++n) {
        int col = colBase + wn * 64 + n * 16 + lr;
        float bv = b2[col];
#pragma unroll
        for (int m = 0; m < 4; ++m)
#pragma unroll
            for (int i = 0; i < 4; ++i) {
                float v = acc[m][n][i] + bv;
                v = v > 0.f ? v : 0.f;
                psum[m][i] += v * b2f(ut16[m][n][i]);
            }
    }
#pragma unroll
    for (int m = 0; m < 4; ++m)
#pragma unroll
        for (int i = 0; i < 4; ++i) {
#pragma unroll
            for (int mask = 1; mask < 16; mask <<= 1)
                psum[m][i] += __shfl_xor(psum[m][i], mask);
        }
    if (lr == 0) {
#pragma unroll
        for (int m = 0; m < 4; ++m) {
            int row0 = rowBase + wm * 64 + m * 16 + lg * 4;
#pragma unroll
            for (int i = 0; i < 4; ++i)
                atomicAdd(&out[row0 + i], psum[m][i]);
        }
    }
}

// ---------- launch ----------
extern "C" void kernel_launch(void* const* d_in, const int* in_sizes, int n_in,
                              void* d_out, int out_size, void* d_ws, size_t ws_size,
                              hipStream_t stream) {
    const float* features = (const float*)d_in[0];
    const float* W1 = (const float*)d_in[1];
    const float* b1 = (const float*)d_in[2];
    const float* W2 = (const float*)d_in[3];
    const float* b2 = (const float*)d_in[4];
    const float* W3 = (const float*)d_in[5];
    const float* b3 = (const float*)d_in[6];
    const float* Wh = (const float*)d_in[7];
    const float* bh = (const float*)d_in[8];
    const float* w  = (const float*)d_in[9];
    float* out = (float*)d_out;

    size_t off = 0;
    auto alloc = [&](size_t bytes) {
        void* p = (char*)d_ws + off;
        off += (bytes + 255) & ~(size_t)255;
        return p;
    };
    u16* featB = (u16*)alloc((size_t)4096 * 1024 * 2);   // 8MB
    u16* W1T   = (u16*)alloc((size_t)2048 * 1024 * 2);   // 4MB
    u16* W2T   = (u16*)alloc((size_t)2048 * 2048 * 2);   // 8MB
    u16* wTb   = (u16*)alloc((size_t)4096 * 512 * 2);    // 4MB
    u16* W34b  = (u16*)alloc((size_t)2048 * 512 * 2);    // 2MB
    float* b34 = (float*)alloc((size_t)512 * 4);
    u16* h1    = (u16*)alloc((size_t)4096 * 2048 * 2);   // 16MB

    // K1: prep — feat cvt, W1T, b34, W34 (f32 VALU, direct bf16 out)
    prep1_kernel<<<898, 256, 0, stream>>>(features, featB, W1, W1T,
                                          W3, Wh, b3, bh, b34, W34b);

    // K2: GEMM1 (exactly 256 heavy) || c->out || W2T/wTb light backfill
    midA_kernel<<<1800, 512, 0, stream>>>(featB, W1T, b1, h1,
                                          b34, w, out, W2, W2T, wTb);

    // K3: fused UT + GEMM2 + dot (atomicAdd into out)
    gemm2dot_kernel<<<256, 512, 0, stream>>>(h1, W2T, b2, wTb, W34b, out);
}

// Round 11
// 183.941 us; speedup vs baseline: 1.3662x; 1.3662x over previous
//
#include <hip/hip_runtime.h>
#include <cstdint>
#include <cstddef>

typedef unsigned short u16;
typedef __attribute__((ext_vector_type(8))) short bf16x8;
typedef __attribute__((ext_vector_type(8))) unsigned short u16x8;
typedef __attribute__((ext_vector_type(4))) unsigned short u16x4;
typedef __attribute__((ext_vector_type(4))) float f32x4;

// ---------- helpers ----------
__device__ __forceinline__ u16 f2b(float f) {
    union { float f; uint32_t u; } v; v.f = f;
    uint32_t u = v.u;
    uint32_t r = (u + 0x7FFFu + ((u >> 16) & 1u)) >> 16;
    return (u16)r;
}
__device__ __forceinline__ float b2f(u16 b) {
    union { uint32_t u; float f; } v; v.u = ((uint32_t)b) << 16;
    return v.f;
}
__device__ __forceinline__ void gload_lds16(const void* g, void* l) {
    __builtin_amdgcn_global_load_lds(
        (const __attribute__((address_space(1))) void*)g,
        (__attribute__((address_space(3))) void*)l,
        16, 0, 0);
}

// ---------- prep building blocks ----------
// fat f32->bf16 convert: 2048 8-elem units per block (256 thr x 8 units)
__device__ __forceinline__ void cvt_fat(const float* __restrict__ in,
                                        u16* __restrict__ outp, int bb, int tid) {
#pragma unroll
    for (int it = 0; it < 8; ++it) {
        size_t u = (size_t)bb * 2048 + (size_t)it * 256 + tid;
        size_t base = u * 8;
        const float4* p = (const float4*)(in + base);
        float4 a = p[0], c = p[1];
        u16x8 o;
        o[0] = f2b(a.x); o[1] = f2b(a.y); o[2] = f2b(a.z); o[3] = f2b(a.w);
        o[4] = f2b(c.x); o[5] = f2b(c.y); o[6] = f2b(c.z); o[7] = f2b(c.w);
        *(u16x8*)(outp + base) = o;
    }
}

// 64x64 f32 tile transpose -> bf16, 256 threads
__device__ __forceinline__ void transpose64_256(const float* __restrict__ in,
                                                u16* __restrict__ outp,
                                                int K, int N, int t, int tid,
                                                float (*tile)[65]) {
    const int ntx = N >> 6;
    const int n0 = (t % ntx) * 64, k0 = (t / ntx) * 64;
    const int r0 = tid >> 4, c4 = tid & 15;
#pragma unroll
    for (int j = 0; j < 4; ++j) {
        int r = r0 + j * 16;
        float4 v = *(const float4*)(in + (size_t)(k0 + r) * N + n0 + c4 * 4);
        tile[r][c4 * 4 + 0] = v.x; tile[r][c4 * 4 + 1] = v.y;
        tile[r][c4 * 4 + 2] = v.z; tile[r][c4 * 4 + 3] = v.w;
    }
    __syncthreads();
    const int rr = tid >> 2;
#pragma unroll
    for (int j = 0; j < 4; ++j) {
        int ch = (tid & 3) + j * 4;
        u16x4 o;
        o[0] = f2b(tile[ch * 4 + 0][rr]); o[1] = f2b(tile[ch * 4 + 1][rr]);
        o[2] = f2b(tile[ch * 4 + 2][rr]); o[3] = f2b(tile[ch * 4 + 3][rr]);
        *(u16x4*)(outp + (size_t)(n0 + rr) * K + k0 + ch * 4) = o;
    }
    __syncthreads();
}

// 64x64 f32 tile transpose -> bf16, 512 threads
__device__ __forceinline__ void transpose64_512(const float* __restrict__ in,
                                                u16* __restrict__ outp,
                                                int K, int N, int t, int tid,
                                                float (*tile)[65]) {
    const int ntx = N >> 6;
    const int n0 = (t % ntx) * 64, k0 = (t / ntx) * 64;
    const int r0 = tid >> 4, c4 = tid & 15;
#pragma unroll
    for (int j = 0; j < 2; ++j) {
        int r = r0 + j * 32;
        float4 v = *(const float4*)(in + (size_t)(k0 + r) * N + n0 + c4 * 4);
        tile[r][c4 * 4 + 0] = v.x; tile[r][c4 * 4 + 1] = v.y;
        tile[r][c4 * 4 + 2] = v.z; tile[r][c4 * 4 + 3] = v.w;
    }
    __syncthreads();
    const int rr = tid >> 3;
#pragma unroll
    for (int j = 0; j < 2; ++j) {
        int ch = (tid & 7) + j * 8;
        u16x4 o;
        o[0] = f2b(tile[ch * 4 + 0][rr]); o[1] = f2b(tile[ch * 4 + 1][rr]);
        o[2] = f2b(tile[ch * 4 + 2][rr]); o[3] = f2b(tile[ch * 4 + 3][rr]);
        *(u16x4*)(outp + (size_t)(n0 + rr) * K + k0 + ch * 4) = o;
    }
    __syncthreads();
}

// ---------- prep1 (256 thr, 546 blocks) ----------
// [0,256)    feat [4096,1024] f32->bf16 (524288 units, exact)
// [256,384)  W3   [2048,1024] f32->bf16 (262144 units, exact)
// [384,512)  W1   [1024,2048] -> W1T (512 tiles, 4/block)
// [512,544)  Wh   [1024,512]  -> WhT (128 tiles, 4/block)
// [544,546)  b34[j] = b3 . Wh[:,j] + bh[j]
__global__ __launch_bounds__(256) void prep1_kernel(
    const float* __restrict__ feat, u16* __restrict__ featB,
    const float* __restrict__ W1, u16* __restrict__ W1T,
    const float* __restrict__ W3, u16* __restrict__ W3c,
    const float* __restrict__ Wh, u16* __restrict__ WhT,
    const float* __restrict__ b3, const float* __restrict__ bh,
    float* __restrict__ b34) {
    __shared__ float tile[64][65];
    const int b = blockIdx.x, tid = threadIdx.x;
    if (b < 256) { cvt_fat(feat, featB, b, tid); return; }
    if (b < 384) { cvt_fat(W3, W3c, b - 256, tid); return; }
    if (b < 512) {
        int g = b - 384;
#pragma unroll
        for (int j = 0; j < 4; ++j)
            transpose64_256(W1, W1T, 1024, 2048, g * 4 + j, tid, tile);
        return;
    }
    if (b < 544) {
        int g = b - 512;
#pragma unroll
        for (int j = 0; j < 4; ++j)
            transpose64_256(Wh, WhT, 1024, 512, g * 4 + j, tid, tile);
        return;
    }
    {
        int j = (b - 544) * 256 + tid;  // [0,512)
        float s = bh[j];
#pragma unroll 4
        for (int k = 0; k < 1024; ++k)
            s += b3[k] * Wh[(size_t)k * 512 + j];
        b34[j] = s;
    }
}

// =====================================================================
// 256x128-tile pipelined GEMM core (round-8-verified, unchanged).
// BK=64, 512 thr = 8 waves (4m x 2n), per-wave 64x64, acc[4][4].
// LDS: 3 buffers x (A 32KB + B 16KB) = 144KB; counted vmcnt(6) gates;
// XOR swizzle ch=(c&7)^(r&7); setprio around MFMA clusters.
// =====================================================================

__device__ __forceinline__ void stage_q(const u16* __restrict__ g, int ldg,
                                        u16* lds, int tid) {
    int r = tid >> 3;
    int ch = (tid & 7) ^ (r & 7);
    gload_lds16(g + (size_t)r * ldg + ch * 8, (char*)lds + tid * 16);
}

__device__ __forceinline__ bf16x8 lds_frag(const u16* s, int row, int kk, int lg) {
    int byte = (row << 7) + (kk << 6) + (lg << 4);
    byte ^= (row & 7) << 4;
    return *(const bf16x8*)((const char*)s + byte);
}

#define MFMA_CLUSTER(AF, BF)                                                   \
    do {                                                                       \
        __builtin_amdgcn_s_setprio(1);                                         \
        _Pragma("unroll") for (int m = 0; m < 4; ++m)                          \
            _Pragma("unroll") for (int n = 0; n < 4; ++n)                      \
                acc[m][n] = __builtin_amdgcn_mfma_f32_16x16x32_bf16(           \
                    AF[m], BF[n], acc[m][n], 0, 0, 0);                         \
        __builtin_amdgcn_s_setprio(0);                                         \
    } while (0)

__device__ __forceinline__ void gemm_loop(
    const u16* __restrict__ Ag, const u16* __restrict__ Bg, int K,
    u16* sA, u16* sB, f32x4 (&acc)[4][4],
    int tid, int wm, int wn, int lr, int lg) {
    const int nt = K >> 6;
    stage_q(Ag, K, sA, tid);
    stage_q(Ag + (size_t)64 * K, K, sA + 4096, tid);
    stage_q(Ag + (size_t)128 * K, K, sA + 8192, tid);
    stage_q(Ag + (size_t)192 * K, K, sA + 12288, tid);
    stage_q(Bg, K, sB, tid);
    stage_q(Bg + (size_t)64 * K, K, sB + 4096, tid);
    stage_q(Ag + 64, K, sA + 16384, tid);
    stage_q(Ag + (size_t)64 * K + 64, K, sA + 16384 + 4096, tid);
    stage_q(Ag + (size_t)128 * K + 64, K, sA + 16384 + 8192, tid);
    stage_q(Ag + (size_t)192 * K + 64, K, sA + 16384 + 12288, tid);
    stage_q(Bg + 64, K, sB + 8192, tid);
    stage_q(Bg + (size_t)64 * K + 64, K, sB + 8192 + 4096, tid);
    asm volatile("s_waitcnt vmcnt(6)" ::: "memory");
    __builtin_amdgcn_sched_barrier(0);
    __builtin_amdgcn_s_barrier();

    for (int t = 0; t < nt; ++t) {
        const int cb = t % 3, nb = (t + 2) % 3;
        const u16* sAc = sA + cb * 16384;
        const u16* sBc = sB + cb * 8192;
        u16* sAn = sA + nb * 16384;
        u16* sBn = sB + nb * 8192;
        const int kb = (t + 2) << 6;
        const bool more2 = (t + 2) < nt;

        // ---- phase 0: kk=0 ----
        bf16x8 a0[4], b0[4];
#pragma unroll
        for (int m = 0; m < 4; ++m)
            a0[m] = lds_frag(sAc + wm * 4096, m * 16 + lr, 0, lg);
#pragma unroll
        for (int n = 0; n < 4; ++n)
            b0[n] = lds_frag(sBc + wn * 4096, n * 16 + lr, 0, lg);
        if (more2) {
            stage_q(Bg + kb, K, sBn, tid);
            stage_q(Bg + (size_t)64 * K + kb, K, sBn + 4096, tid);
            stage_q(Ag + kb, K, sAn, tid);
        }
        asm volatile("s_waitcnt lgkmcnt(0)" ::: "memory");
        __builtin_amdgcn_sched_barrier(0);
        MFMA_CLUSTER(a0, b0);
        __builtin_amdgcn_s_barrier();

        // ---- phase 1: kk=1; gate ----
        bf16x8 a1[4], b1[4];
#pragma unroll
        for (int m = 0; m < 4; ++m)
            a1[m] = lds_frag(sAc + wm * 4096, m * 16 + lr, 1, lg);
#pragma unroll
        for (int n = 0; n < 4; ++n)
            b1[n] = lds_frag(sBc + wn * 4096, n * 16 + lr, 1, lg);
        if (more2) {
            stage_q(Ag + (size_t)64 * K + kb, K, sAn + 4096, tid);
            stage_q(Ag + (size_t)128 * K + kb, K, sAn + 8192, tid);
            stage_q(Ag + (size_t)192 * K + kb, K, sAn + 12288, tid);
            asm volatile("s_waitcnt vmcnt(6)" ::: "memory");
        } else if (t + 1 < nt) {
            asm volatile("s_waitcnt vmcnt(0)" ::: "memory");
        }
        __builtin_amdgcn_sched_barrier(0);
        asm volatile("s_waitcnt lgkmcnt(0)" ::: "memory");
        __builtin_amdgcn_sched_barrier(0);
        MFMA_CLUSTER(a1, b1);
        __builtin_amdgcn_s_barrier();
    }
}

template <int RELU, int HB>
__device__ __forceinline__ void gemm_store(
    const u16* __restrict__ A, const u16* __restrict__ BT,
    const float* __restrict__ bias, u16* __restrict__ C,
    int N, int K, int bx, int by, u16* sA, u16* sB) {
    const int tid = threadIdx.x;
    const int lane = tid & 63;
    const int wv = tid >> 6;
    const int wm = wv >> 1, wn = wv & 1;
    const int lr = lane & 15, lg = lane >> 4;
    const int rowBase = by * 256, colBase = bx * 128;
    f32x4 acc[4][4] = {};
    gemm_loop(A + (size_t)rowBase * K, BT + (size_t)colBase * K, K,
              sA, sB, acc, tid, wm, wn, lr, lg);
#pragma unroll
    for (int n = 0; n < 4; ++n) {
        int col = colBase + wn * 64 + n * 16 + lr;
        float bv = HB ? bias[col] : 0.f;
#pragma unroll
        for (int m = 0; m < 4; ++m) {
            int row0 = rowBase + wm * 64 + m * 16 + lg * 4;
#pragma unroll
            for (int i = 0; i < 4; ++i) {
                float v = acc[m][n][i] + bv;
                if (RELU) v = v > 0.f ? v : 0.f;
                C[(size_t)(row0 + i) * N + col] = f2b(v);
            }
        }
    }
}

// ---------- K2: midA (512 thr, 1832 blocks) ----------
// [0,256)      GEMM1: h1 = relu(featB @ W1T^T + b1)  M=4096 N=2048 K=1024
// [256,288)    W34 = W3c @ WhT^T                     M=2048 N=512  K=1024
// [288,296)    out[n] = c[n] = b34 . w[:,n]
// [296,1320)   W2 [2048,2048] -> W2T (1024 tiles)
// [1320,1832)  w  [512,4096]  -> wTb (512 tiles)
__global__ __launch_bounds__(512, 2) void midA_kernel(
    const u16* __restrict__ featB, const u16* __restrict__ W1T,
    const float* __restrict__ b1, u16* __restrict__ h1,
    const u16* __restrict__ W3c, const u16* __restrict__ WhT, u16* __restrict__ W34,
    const float* __restrict__ b34, const float* __restrict__ w,
    float* __restrict__ out,
    const float* __restrict__ W2, u16* __restrict__ W2T,
    u16* __restrict__ wTb) {
    __shared__ __align__(16) u16 sA[3 * 16384];
    __shared__ __align__(16) u16 sB[3 * 8192];
    const int b = blockIdx.x, tid = threadIdx.x;
    if (b < 256) {
        gemm_store<1, 1>(featB, W1T, b1, h1, 2048, 1024, b & 15, b >> 4, sA, sB);
    } else if (b < 288) {
        int g = b - 256;
        gemm_store<0, 0>(W3c, WhT, nullptr, W34, 512, 1024, g & 3, g >> 2, sA, sB);
    } else if (b < 296) {
        int n = (b - 288) * 512 + tid;  // [0,4096)
        float s = 0.f;
#pragma unroll 4
        for (int j = 0; j < 512; ++j)
            s += b34[j] * w[(size_t)j * 4096 + n];
        out[n] = s;
    } else if (b < 1320) {
        transpose64_512(W2, W2T, 2048, 2048, b - 296, tid, (float(*)[65])sA);
    } else {
        transpose64_512(w, wTb, 512, 4096, b - 1320, tid, (float(*)[65])sA);
    }
}

// ---------- K3: fused UT + GEMM2 + row-dot (512 thr, 256 blocks) ----------
__global__ __launch_bounds__(512, 2) void gemm2dot_kernel(
    const u16* __restrict__ h1, const u16* __restrict__ W2T,
    const float* __restrict__ b2,
    const u16* __restrict__ wTb, const u16* __restrict__ W34,
    float* __restrict__ out) {
    __shared__ __align__(16) u16 sA[3 * 16384];
    __shared__ __align__(16) u16 sB[3 * 8192];
    const int tid = threadIdx.x;
    const int lane = tid & 63;
    const int wv = tid >> 6;
    const int wm = wv >> 1, wn = wv & 1;
    const int lr = lane & 15, lg = lane >> 4;
    const int by = blockIdx.x >> 4, bx = blockIdx.x & 15;
    const int rowBase = by * 256, colBase = bx * 128;

    f32x4 acc[4][4] = {};
    // phase A: UT sub-tile in registers (K=512)
    gemm_loop(wTb + (size_t)rowBase * 512, W34 + (size_t)colBase * 512, 512,
              sA, sB, acc, tid, wm, wn, lr, lg);
    u16x4 ut16[4][4];
#pragma unroll
    for (int m = 0; m < 4; ++m)
#pragma unroll
        for (int n = 0; n < 4; ++n) {
#pragma unroll
            for (int i = 0; i < 4; ++i) ut16[m][n][i] = f2b(acc[m][n][i]);
            acc[m][n] = (f32x4){0.f, 0.f, 0.f, 0.f};
        }
    // phase B: GEMM2 (K=2048)
    gemm_loop(h1 + (size_t)rowBase * 2048, W2T + (size_t)colBase * 2048, 2048,
              sA, sB, acc, tid, wm, wn, lr, lg);
    // epilogue: relu + dot with ut16, lane-reduce, atomicAdd
    float psum[4][4] = {};
#pragma unroll
    for (int n = 0; n < 4; ++n) {
        int col = colBase + wn * 64 + n * 16 + lr;
        float bv = b2[col];
#pragma unroll
        for (int m = 0; m < 4; ++m)
#pragma unroll
            for (int i = 0; i < 4; ++i) {
                float v = acc[m][n][i] + bv;
                v = v > 0.f ? v : 0.f;
                psum[m][i] += v * b2f(ut16[m][n][i]);
            }
    }
#pragma unroll
    for (int m = 0; m < 4; ++m)
#pragma unroll
        for (int i = 0; i < 4; ++i) {
#pragma unroll
            for (int mask = 1; mask < 16; mask <<= 1)
                psum[m][i] += __shfl_xor(psum[m][i], mask);
        }
    if (lr == 0) {
#pragma unroll
        for (int m = 0; m < 4; ++m) {
            int row0 = rowBase + wm * 64 + m * 16 + lg * 4;
#pragma unroll
            for (int i = 0; i < 4; ++i)
                atomicAdd(&out[row0 + i], psum[m][i]);
        }
    }
}

// ---------- launch ----------
extern "C" void kernel_launch(void* const* d_in, const int* in_sizes, int n_in,
                              void* d_out, int out_size, void* d_ws, size_t ws_size,
                              hipStream_t stream) {
    const float* features = (const float*)d_in[0];
    const float* W1 = (const float*)d_in[1];
    const float* b1 = (const float*)d_in[2];
    const float* W2 = (const float*)d_in[3];
    const float* b2 = (const float*)d_in[4];
    const float* W3 = (const float*)d_in[5];
    const float* b3 = (const float*)d_in[6];
    const float* Wh = (const float*)d_in[7];
    const float* bh = (const float*)d_in[8];
    const float* w  = (const float*)d_in[9];
    float* out = (float*)d_out;

    size_t off = 0;
    auto alloc = [&](size_t bytes) {
        void* p = (char*)d_ws + off;
        off += (bytes + 255) & ~(size_t)255;
        return p;
    };
    u16* featB = (u16*)alloc((size_t)4096 * 1024 * 2);   // 8MB
    u16* W3c   = (u16*)alloc((size_t)2048 * 1024 * 2);   // 4MB
    u16* W1T   = (u16*)alloc((size_t)2048 * 1024 * 2);   // 4MB
    u16* WhT   = (u16*)alloc((size_t)512 * 1024 * 2);    // 1MB
    u16* W2T   = (u16*)alloc((size_t)2048 * 2048 * 2);   // 8MB
    u16* wTb   = (u16*)alloc((size_t)4096 * 512 * 2);    // 4MB
    u16* W34   = (u16*)alloc((size_t)2048 * 512 * 2);    // 2MB
    float* b34 = (float*)alloc((size_t)512 * 4);
    u16* h1    = (u16*)alloc((size_t)4096 * 2048 * 2);   // 16MB

    // K1: prep — featB, W3c, W1T, WhT, b34 (all streaming, fat blocks)
    prep1_kernel<<<546, 256, 0, stream>>>(features, featB, W1, W1T,
                                          W3, W3c, Wh, WhT, b3, bh, b34);

    // K2: GEMM1 (256) || W34-GEMM (32) || c->out || W2T/wTb light backfill
    midA_kernel<<<1832, 512, 0, stream>>>(featB, W1T, b1, h1,
                                          W3c, WhT, W34, b34, w, out,
                                          W2, W2T, wTb);

    // K3: fused UT + GEMM2 + dot (atomicAdd into out)
    gemm2dot_kernel<<<256, 512, 0, stream>>>(h1, W2T, b2, wTb, W34, out);
}

// Round 12
// 100.965 us; speedup vs baseline: 2.4890x; 1.8218x over previous
//
#include <hip/hip_runtime.h>
#include <cstdint>
#include <cstddef>

typedef unsigned short u16;
typedef __attribute__((ext_vector_type(8))) short bf16x8;
typedef __attribute__((ext_vector_type(8))) unsigned short u16x8;
typedef __attribute__((ext_vector_type(4))) unsigned short u16x4;
typedef __attribute__((ext_vector_type(4))) float f32x4;

// ---------- helpers ----------
__device__ __forceinline__ u16 f2b(float f) {
    union { float f; uint32_t u; } v; v.f = f;
    uint32_t u = v.u;
    uint32_t r = (u + 0x7FFFu + ((u >> 16) & 1u)) >> 16;
    return (u16)r;
}
__device__ __forceinline__ float b2f(u16 b) {
    union { uint32_t u; float f; } v; v.u = ((uint32_t)b) << 16;
    return v.f;
}
__device__ __forceinline__ void gload_lds16(const void* g, void* l) {
    __builtin_amdgcn_global_load_lds(
        (const __attribute__((address_space(1))) void*)g,
        (__attribute__((address_space(3))) void*)l,
        16, 0, 0);
}

// ---------- prep building blocks ----------
// fat f32->bf16 convert: 2048 8-elem units per block (256 thr x 8 units)
__device__ __forceinline__ void cvt_fat(const float* __restrict__ in,
                                        u16* __restrict__ outp, int bb, int tid) {
#pragma unroll
    for (int it = 0; it < 8; ++it) {
        size_t u = (size_t)bb * 2048 + (size_t)it * 256 + tid;
        size_t base = u * 8;
        const float4* p = (const float4*)(in + base);
        float4 a = p[0], c = p[1];
        u16x8 o;
        o[0] = f2b(a.x); o[1] = f2b(a.y); o[2] = f2b(a.z); o[3] = f2b(a.w);
        o[4] = f2b(c.x); o[5] = f2b(c.y); o[6] = f2b(c.z); o[7] = f2b(c.w);
        *(u16x8*)(outp + base) = o;
    }
}

// 64x64 f32 tile transpose -> bf16, 256 threads
__device__ __forceinline__ void transpose64_256(const float* __restrict__ in,
                                                u16* __restrict__ outp,
                                                int K, int N, int t, int tid,
                                                float (*tile)[65]) {
    const int ntx = N >> 6;
    const int n0 = (t % ntx) * 64, k0 = (t / ntx) * 64;
    const int r0 = tid >> 4, c4 = tid & 15;
#pragma unroll
    for (int j = 0; j < 4; ++j) {
        int r = r0 + j * 16;
        float4 v = *(const float4*)(in + (size_t)(k0 + r) * N + n0 + c4 * 4);
        tile[r][c4 * 4 + 0] = v.x; tile[r][c4 * 4 + 1] = v.y;
        tile[r][c4 * 4 + 2] = v.z; tile[r][c4 * 4 + 3] = v.w;
    }
    __syncthreads();
    const int rr = tid >> 2;
#pragma unroll
    for (int j = 0; j < 4; ++j) {
        int ch = (tid & 3) + j * 4;
        u16x4 o;
        o[0] = f2b(tile[ch * 4 + 0][rr]); o[1] = f2b(tile[ch * 4 + 1][rr]);
        o[2] = f2b(tile[ch * 4 + 2][rr]); o[3] = f2b(tile[ch * 4 + 3][rr]);
        *(u16x4*)(outp + (size_t)(n0 + rr) * K + k0 + ch * 4) = o;
    }
    __syncthreads();
}

// 64x64 f32 tile transpose -> bf16, 512 threads
__device__ __forceinline__ void transpose64_512(const float* __restrict__ in,
                                                u16* __restrict__ outp,
                                                int K, int N, int t, int tid,
                                                float (*tile)[65]) {
    const int ntx = N >> 6;
    const int n0 = (t % ntx) * 64, k0 = (t / ntx) * 64;
    const int r0 = tid >> 4, c4 = tid & 15;
#pragma unroll
    for (int j = 0; j < 2; ++j) {
        int r = r0 + j * 32;
        float4 v = *(const float4*)(in + (size_t)(k0 + r) * N + n0 + c4 * 4);
        tile[r][c4 * 4 + 0] = v.x; tile[r][c4 * 4 + 1] = v.y;
        tile[r][c4 * 4 + 2] = v.z; tile[r][c4 * 4 + 3] = v.w;
    }
    __syncthreads();
    const int rr = tid >> 3;
#pragma unroll
    for (int j = 0; j < 2; ++j) {
        int ch = (tid & 7) + j * 8;
        u16x4 o;
        o[0] = f2b(tile[ch * 4 + 0][rr]); o[1] = f2b(tile[ch * 4 + 1][rr]);
        o[2] = f2b(tile[ch * 4 + 2][rr]); o[3] = f2b(tile[ch * 4 + 3][rr]);
        *(u16x4*)(outp + (size_t)(n0 + rr) * K + k0 + ch * 4) = o;
    }
    __syncthreads();
}

// ---------- prep1 (256 thr, 576 blocks) ----------
// [0,256)    feat [4096,1024] f32->bf16 (524288 units, exact)
// [256,384)  W3   [2048,1024] f32->bf16 (262144 units, exact)
// [384,512)  W1   [1024,2048] -> W1T (512 tiles, 4/block)
// [512,544)  Wh   [1024,512]  -> WhT (128 tiles, 4/block)
// [544,576)  b34[j] = b3 . Wh[:,j] + bh[j]  — 32 blocks, k-split 16-way
__global__ __launch_bounds__(256) void prep1_kernel(
    const float* __restrict__ feat, u16* __restrict__ featB,
    const float* __restrict__ W1, u16* __restrict__ W1T,
    const float* __restrict__ W3, u16* __restrict__ W3c,
    const float* __restrict__ Wh, u16* __restrict__ WhT,
    const float* __restrict__ b3, const float* __restrict__ bh,
    float* __restrict__ b34) {
    __shared__ float tile[64][65];
    const int b = blockIdx.x, tid = threadIdx.x;
    if (b < 256) { cvt_fat(feat, featB, b, tid); return; }
    if (b < 384) { cvt_fat(W3, W3c, b - 256, tid); return; }
    if (b < 512) {
        int g = b - 384;
#pragma unroll
        for (int j = 0; j < 4; ++j)
            transpose64_256(W1, W1T, 1024, 2048, g * 4 + j, tid, tile);
        return;
    }
    if (b < 544) {
        int g = b - 512;
#pragma unroll
        for (int j = 0; j < 4; ++j)
            transpose64_256(Wh, WhT, 1024, 512, g * 4 + j, tid, tile);
        return;
    }
    {   // b34: block g handles 16 j's; 16 k-groups of 64; LDS reduce
        int g = b - 544;                 // [0,32)
        int jl = tid & 15, kg = tid >> 4;
        int j = g * 16 + jl;
        float s = 0.f;
#pragma unroll 8
        for (int kk = 0; kk < 64; ++kk) {
            int k = kg * 64 + kk;
            s += b3[k] * Wh[(size_t)k * 512 + j];
        }
        tile[kg][jl] = s;
        __syncthreads();
        if (kg == 0) {
            float t = bh[j];
#pragma unroll
            for (int q = 0; q < 16; ++q) t += tile[q][jl];
            b34[j] = t;
        }
    }
}

// =====================================================================
// 256x128-tile pipelined GEMM core (round-8-verified, unchanged).
// BK=64, 512 thr = 8 waves (4m x 2n), per-wave 64x64, acc[4][4].
// LDS: 3 buffers x (A 32KB + B 16KB) = 144KB; counted vmcnt(6) gates;
// XOR swizzle ch=(c&7)^(r&7); setprio around MFMA clusters.
// =====================================================================

__device__ __forceinline__ void stage_q(const u16* __restrict__ g, int ldg,
                                        u16* lds, int tid) {
    int r = tid >> 3;
    int ch = (tid & 7) ^ (r & 7);
    gload_lds16(g + (size_t)r * ldg + ch * 8, (char*)lds + tid * 16);
}

__device__ __forceinline__ bf16x8 lds_frag(const u16* s, int row, int kk, int lg) {
    int byte = (row << 7) + (kk << 6) + (lg << 4);
    byte ^= (row & 7) << 4;
    return *(const bf16x8*)((const char*)s + byte);
}

#define MFMA_CLUSTER(AF, BF)                                                   \
    do {                                                                       \
        __builtin_amdgcn_s_setprio(1);                                         \
        _Pragma("unroll") for (int m = 0; m < 4; ++m)                          \
            _Pragma("unroll") for (int n = 0; n < 4; ++n)                      \
                acc[m][n] = __builtin_amdgcn_mfma_f32_16x16x32_bf16(           \
                    AF[m], BF[n], acc[m][n], 0, 0, 0);                         \
        __builtin_amdgcn_s_setprio(0);                                         \
    } while (0)

__device__ __forceinline__ void gemm_loop(
    const u16* __restrict__ Ag, const u16* __restrict__ Bg, int K,
    u16* sA, u16* sB, f32x4 (&acc)[4][4],
    int tid, int wm, int wn, int lr, int lg) {
    const int nt = K >> 6;
    stage_q(Ag, K, sA, tid);
    stage_q(Ag + (size_t)64 * K, K, sA + 4096, tid);
    stage_q(Ag + (size_t)128 * K, K, sA + 8192, tid);
    stage_q(Ag + (size_t)192 * K, K, sA + 12288, tid);
    stage_q(Bg, K, sB, tid);
    stage_q(Bg + (size_t)64 * K, K, sB + 4096, tid);
    stage_q(Ag + 64, K, sA + 16384, tid);
    stage_q(Ag + (size_t)64 * K + 64, K, sA + 16384 + 4096, tid);
    stage_q(Ag + (size_t)128 * K + 64, K, sA + 16384 + 8192, tid);
    stage_q(Ag + (size_t)192 * K + 64, K, sA + 16384 + 12288, tid);
    stage_q(Bg + 64, K, sB + 8192, tid);
    stage_q(Bg + (size_t)64 * K + 64, K, sB + 8192 + 4096, tid);
    asm volatile("s_waitcnt vmcnt(6)" ::: "memory");
    __builtin_amdgcn_sched_barrier(0);
    __builtin_amdgcn_s_barrier();

    for (int t = 0; t < nt; ++t) {
        const int cb = t % 3, nb = (t + 2) % 3;
        const u16* sAc = sA + cb * 16384;
        const u16* sBc = sB + cb * 8192;
        u16* sAn = sA + nb * 16384;
        u16* sBn = sB + nb * 8192;
        const int kb = (t + 2) << 6;
        const bool more2 = (t + 2) < nt;

        // ---- phase 0: kk=0 ----
        bf16x8 a0[4], b0[4];
#pragma unroll
        for (int m = 0; m < 4; ++m)
            a0[m] = lds_frag(sAc + wm * 4096, m * 16 + lr, 0, lg);
#pragma unroll
        for (int n = 0; n < 4; ++n)
            b0[n] = lds_frag(sBc + wn * 4096, n * 16 + lr, 0, lg);
        if (more2) {
            stage_q(Bg + kb, K, sBn, tid);
            stage_q(Bg + (size_t)64 * K + kb, K, sBn + 4096, tid);
            stage_q(Ag + kb, K, sAn, tid);
        }
        asm volatile("s_waitcnt lgkmcnt(0)" ::: "memory");
        __builtin_amdgcn_sched_barrier(0);
        MFMA_CLUSTER(a0, b0);
        __builtin_amdgcn_s_barrier();

        // ---- phase 1: kk=1; gate ----
        bf16x8 a1[4], b1[4];
#pragma unroll
        for (int m = 0; m < 4; ++m)
            a1[m] = lds_frag(sAc + wm * 4096, m * 16 + lr, 1, lg);
#pragma unroll
        for (int n = 0; n < 4; ++n)
            b1[n] = lds_frag(sBc + wn * 4096, n * 16 + lr, 1, lg);
        if (more2) {
            stage_q(Ag + (size_t)64 * K + kb, K, sAn + 4096, tid);
            stage_q(Ag + (size_t)128 * K + kb, K, sAn + 8192, tid);
            stage_q(Ag + (size_t)192 * K + kb, K, sAn + 12288, tid);
            asm volatile("s_waitcnt vmcnt(6)" ::: "memory");
        } else if (t + 1 < nt) {
            asm volatile("s_waitcnt vmcnt(0)" ::: "memory");
        }
        __builtin_amdgcn_sched_barrier(0);
        asm volatile("s_waitcnt lgkmcnt(0)" ::: "memory");
        __builtin_amdgcn_sched_barrier(0);
        MFMA_CLUSTER(a1, b1);
        __builtin_amdgcn_s_barrier();
    }
}

template <int RELU, int HB>
__device__ __forceinline__ void gemm_store(
    const u16* __restrict__ A, const u16* __restrict__ BT,
    const float* __restrict__ bias, u16* __restrict__ C,
    int N, int K, int bx, int by, u16* sA, u16* sB) {
    const int tid = threadIdx.x;
    const int lane = tid & 63;
    const int wv = tid >> 6;
    const int wm = wv >> 1, wn = wv & 1;
    const int lr = lane & 15, lg = lane >> 4;
    const int rowBase = by * 256, colBase = bx * 128;
    f32x4 acc[4][4] = {};
    gemm_loop(A + (size_t)rowBase * K, BT + (size_t)colBase * K, K,
              sA, sB, acc, tid, wm, wn, lr, lg);
#pragma unroll
    for (int n = 0; n < 4; ++n) {
        int col = colBase + wn * 64 + n * 16 + lr;
        float bv = HB ? bias[col] : 0.f;
#pragma unroll
        for (int m = 0; m < 4; ++m) {
            int row0 = rowBase + wm * 64 + m * 16 + lg * 4;
#pragma unroll
            for (int i = 0; i < 4; ++i) {
                float v = acc[m][n][i] + bv;
                if (RELU) v = v > 0.f ? v : 0.f;
                C[(size_t)(row0 + i) * N + col] = f2b(v);
            }
        }
    }
}

// ---------- K2: midA (512 thr, 1888 blocks) ----------
// [0,256)      GEMM1: h1 = relu(featB @ W1T^T + b1)  M=4096 N=2048 K=1024
// [256,288)    W34 = W3c @ WhT^T                     M=2048 N=512  K=1024
// [288,352)    out[n] = c[n] = b34 . w[:,n]  — 64 blocks, j-split 8-way
// [352,1376)   W2 [2048,2048] -> W2T (1024 tiles)
// [1376,1888)  w  [512,4096]  -> wTb (512 tiles)
__global__ __launch_bounds__(512, 2) void midA_kernel(
    const u16* __restrict__ featB, const u16* __restrict__ W1T,
    const float* __restrict__ b1, u16* __restrict__ h1,
    const u16* __restrict__ W3c, const u16* __restrict__ WhT, u16* __restrict__ W34,
    const float* __restrict__ b34, const float* __restrict__ w,
    float* __restrict__ out,
    const float* __restrict__ W2, u16* __restrict__ W2T,
    u16* __restrict__ wTb) {
    __shared__ __align__(16) u16 sA[3 * 16384];
    __shared__ __align__(16) u16 sB[3 * 8192];
    const int b = blockIdx.x, tid = threadIdx.x;
    if (b < 256) {
        gemm_store<1, 1>(featB, W1T, b1, h1, 2048, 1024, b & 15, b >> 4, sA, sB);
    } else if (b < 288) {
        int g = b - 256;
        gemm_store<0, 0>(W3c, WhT, nullptr, W34, 512, 1024, g & 3, g >> 2, sA, sB);
    } else if (b < 352) {
        // c: block g handles 64 n's; 8 j-groups of 64; LDS reduce
        int g = b - 288;                 // [0,64)
        int nl = tid & 63, jg = tid >> 6;
        int n = g * 64 + nl;
        float s = 0.f;
#pragma unroll 8
        for (int jj = 0; jj < 64; ++jj) {
            int j = jg * 64 + jj;
            s += b34[j] * w[(size_t)j * 4096 + n];
        }
        float* red = (float*)sA;         // 8 x 64 floats
        red[jg * 64 + nl] = s;
        __syncthreads();
        if (jg == 0) {
            float t = 0.f;
#pragma unroll
            for (int q = 0; q < 8; ++q) t += red[q * 64 + nl];
            out[n] = t;
        }
    } else if (b < 1376) {
        transpose64_512(W2, W2T, 2048, 2048, b - 352, tid, (float(*)[65])sA);
    } else {
        transpose64_512(w, wTb, 512, 4096, b - 1376, tid, (float(*)[65])sA);
    }
}

// ---------- K3: fused UT + GEMM2 + row-dot (512 thr, 256 blocks) ----------
__global__ __launch_bounds__(512, 2) void gemm2dot_kernel(
    const u16* __restrict__ h1, const u16* __restrict__ W2T,
    const float* __restrict__ b2,
    const u16* __restrict__ wTb, const u16* __restrict__ W34,
    float* __restrict__ out) {
    __shared__ __align__(16) u16 sA[3 * 16384];
    __shared__ __align__(16) u16 sB[3 * 8192];
    const int tid = threadIdx.x;
    const int lane = tid & 63;
    const int wv = tid >> 6;
    const int wm = wv >> 1, wn = wv & 1;
    const int lr = lane & 15, lg = lane >> 4;
    const int by = blockIdx.x >> 4, bx = blockIdx.x & 15;
    const int rowBase = by * 256, colBase = bx * 128;

    f32x4 acc[4][4] = {};
    // phase A: UT sub-tile in registers (K=512)
    gemm_loop(wTb + (size_t)rowBase * 512, W34 + (size_t)colBase * 512, 512,
              sA, sB, acc, tid, wm, wn, lr, lg);
    u16x4 ut16[4][4];
#pragma unroll
    for (int m = 0; m < 4; ++m)
#pragma unroll
        for (int n = 0; n < 4; ++n) {
#pragma unroll
            for (int i = 0; i < 4; ++i) ut16[m][n][i] = f2b(acc[m][n][i]);
            acc[m][n] = (f32x4){0.f, 0.f, 0.f, 0.f};
        }
    // phase B: GEMM2 (K=2048)
    gemm_loop(h1 + (size_t)rowBase * 2048, W2T + (size_t)colBase * 2048, 2048,
              sA, sB, acc, tid, wm, wn, lr, lg);
    // epilogue: relu + dot with ut16, lane-reduce, atomicAdd
    float psum[4][4] = {};
#pragma unroll
    for (int n = 0; n < 4; ++n) {
        int col = colBase + wn * 64 + n * 16 + lr;
        float bv = b2[col];
#pragma unroll
        for (int m = 0; m < 4; ++m)
#pragma unroll
            for (int i = 0; i < 4; ++i) {
                float v = acc[m][n][i] + bv;
                v = v > 0.f ? v : 0.f;
                psum[m][i] += v * b2f(ut16[m][n][i]);
            }
    }
#pragma unroll
    for (int m = 0; m < 4; ++m)
#pragma unroll
        for (int i = 0; i < 4; ++i) {
#pragma unroll
            for (int mask = 1; mask < 16; mask <<= 1)
                psum[m][i] += __shfl_xor(psum[m][i], mask);
        }
    if (lr == 0) {
#pragma unroll
        for (int m = 0; m < 4; ++m) {
            int row0 = rowBase + wm * 64 + m * 16 + lg * 4;
#pragma unroll
            for (int i = 0; i < 4; ++i)
                atomicAdd(&out[row0 + i], psum[m][i]);
        }
    }
}

// ---------- launch ----------
extern "C" void kernel_launch(void* const* d_in, const int* in_sizes, int n_in,
                              void* d_out, int out_size, void* d_ws, size_t ws_size,
                              hipStream_t stream) {
    const float* features = (const float*)d_in[0];
    const float* W1 = (const float*)d_in[1];
    const float* b1 = (const float*)d_in[2];
    const float* W2 = (const float*)d_in[3];
    const float* b2 = (const float*)d_in[4];
    const float* W3 = (const float*)d_in[5];
    const float* b3 = (const float*)d_in[6];
    const float* Wh = (const float*)d_in[7];
    const float* bh = (const float*)d_in[8];
    const float* w  = (const float*)d_in[9];
    float* out = (float*)d_out;

    size_t off = 0;
    auto alloc = [&](size_t bytes) {
        void* p = (char*)d_ws + off;
        off += (bytes + 255) & ~(size_t)255;
        return p;
    };
    u16* featB = (u16*)alloc((size_t)4096 * 1024 * 2);   // 8MB
    u16* W3c   = (u16*)alloc((size_t)2048 * 1024 * 2);   // 4MB
    u16* W1T   = (u16*)alloc((size_t)2048 * 1024 * 2);   // 4MB
    u16* WhT   = (u16*)alloc((size_t)512 * 1024 * 2);    // 1MB
    u16* W2T   = (u16*)alloc((size_t)2048 * 2048 * 2);   // 8MB
    u16* wTb   = (u16*)alloc((size_t)4096 * 512 * 2);    // 4MB
    u16* W34   = (u16*)alloc((size_t)2048 * 512 * 2);    // 2MB
    float* b34 = (float*)alloc((size_t)512 * 4);
    u16* h1    = (u16*)alloc((size_t)4096 * 2048 * 2);   // 16MB

    // K1: prep — featB, W3c, W1T, WhT, b34 (k-split)
    prep1_kernel<<<576, 256, 0, stream>>>(features, featB, W1, W1T,
                                          W3, W3c, Wh, WhT, b3, bh, b34);

    // K2: GEMM1 (256) || W34-GEMM (32) || c (64) || W2T/wTb backfill
    midA_kernel<<<1888, 512, 0, stream>>>(featB, W1T, b1, h1,
                                          W3c, WhT, W34, b34, w, out,
                                          W2, W2T, wTb);

    // K3: fused UT + GEMM2 + dot (atomicAdd into out)
    gemm2dot_kernel<<<256, 512, 0, stream>>>(h1, W2T, b2, wTb, W34, out);
}